// Round 6
// baseline (275.480 us; speedup 1.0000x reference)
//
#include <hip/hip_runtime.h>
#include <hip/hip_bf16.h>
#include <math.h>

#define BSZ 8
#define LQ  1024
#define LV  13294
#define NH  8
#define HD  32
#define VM  (BSZ * LV)   // 106352 rows of value

typedef __attribute__((ext_vector_type(8))) short bf16x8;
typedef __attribute__((ext_vector_type(4))) float f32x4;

__device__ static inline unsigned short f2bf(float f) {
    unsigned int u = __float_as_uint(f);
    unsigned int r = (u + 0x7FFFu + ((u >> 16) & 1u)) >> 16;
    return (unsigned short)r;
}
__device__ static inline float bf2f(unsigned short s) {
    return __uint_as_float(((unsigned int)s) << 16);
}
__device__ static inline unsigned int pk2bf(float a, float b) {
    __hip_bfloat162 h = __float22bfloat162_rn(make_float2(a, b));
    return *(unsigned int*)&h;
}

// ---------------------------------------------------------------------------
// Transpose+convert vp_w and op_w [k][n] f32 -> [n][k] bf16. Grid 512.
// ---------------------------------------------------------------------------
__global__ __launch_bounds__(256) void wconv_kernel(
    const float* __restrict__ w0, const float* __restrict__ w1,
    unsigned short* __restrict__ t0, unsigned short* __restrict__ t1)
{
    const int n = blockIdx.x & 255;
    const int k = threadIdx.x;
    if (blockIdx.x < 256) t0[n * 256 + k] = f2bf(w0[k * 256 + n]);
    else                  t1[n * 256 + k] = f2bf(w1[k * 256 + n]);
}

// ---------------------------------------------------------------------------
// vproj v7: v = value @ vp_w + vp_b -> [b][h][pix][c] bf16.
// A-tile (64 rows x 256 K, bf16) staged to LDS ONCE (XOR-swizzled), single
// barrier. W (128 KB, L2-hot) loaded from global inside the K-loop — no
// barriers, no vmcnt-drain stalls. Swapped MFMA operands: lane = pix,
// regs = channels -> packed 8 B stores. 32 KB LDS -> 5 blocks/CU.
// ---------------------------------------------------------------------------
__global__ __launch_bounds__(256, 4) void vproj_mfma_kernel(
    const float* __restrict__ A,            // [VM][256] f32
    const unsigned short* __restrict__ wT,  // [256][256] bf16 [n][k]
    const float* __restrict__ bias,         // [256]
    unsigned short* __restrict__ v)         // [B][H][LV][32] bf16
{
    __shared__ __align__(16) unsigned short Asb[64 * 256];  // 32 KB

    const int tid  = threadIdx.x;
    const int w    = tid >> 6;
    const int lane = tid & 63;
    const int mrow = lane & 15;
    const int quad = lane >> 4;
    const int m0   = blockIdx.x * 64;

    // ---- stage A tile once: f32 -> bf16, XOR-swizzled 16 B chunks ----
    {
        const int row = tid >> 2;          // 0..63
        const int seg = tid & 3;           // 64-float segment
        int gm = m0 + row; if (gm >= VM) gm = VM - 1;
        const float* ap = A + (size_t)gm * 256 + seg * 64;
        unsigned short* lrow = &Asb[row * 256];
#pragma unroll
        for (int u = 0; u < 8; ++u) {
            const float4 f0 = *(const float4*)(ap + u * 8);
            const float4 f1 = *(const float4*)(ap + u * 8 + 4);
            uint4 pk;
            pk.x = pk2bf(f0.x, f0.y); pk.y = pk2bf(f0.z, f0.w);
            pk.z = pk2bf(f1.x, f1.y); pk.w = pk2bf(f1.z, f1.w);
            const int c  = seg * 8 + u;          // logical 16 B chunk 0..31
            const int cp = c ^ (row & 31);       // swizzle
            *(uint4*)(lrow + cp * 8) = pk;
        }
    }
    __syncthreads();

    // ---- K-loop: no barriers. W from global (L2), A from LDS. ----
    f32x4 acc[4][4];
#pragma unroll
    for (int i = 0; i < 4; ++i)
#pragma unroll
        for (int j = 0; j < 4; ++j) acc[i][j] = (f32x4)0.f;

#pragma unroll
    for (int kc = 0; kc < 8; ++kc) {
        bf16x8 wfr[4], af[4];
#pragma unroll
        for (int j = 0; j < 4; ++j) {
            const int n = w * 64 + j * 16 + mrow;
            wfr[j] = *(const bf16x8*)(const void*)(wT + (size_t)n * 256 + kc * 32 + quad * 8);
        }
#pragma unroll
        for (int i = 0; i < 4; ++i) {
            const int mr = i * 16 + mrow;
            const int cp = (kc * 4 + quad) ^ (mr & 31);
            af[i] = *(const bf16x8*)(const void*)&Asb[mr * 256 + cp * 8];
        }
#pragma unroll
        for (int i = 0; i < 4; ++i)
#pragma unroll
            for (int j = 0; j < 4; ++j)
                acc[i][j] = __builtin_amdgcn_mfma_f32_16x16x32_bf16(
                    wfr[j], af[i], acc[i][j], 0, 0, 0);
    }

    // ---- epilogue (validated R4/R5): lane = pix, regs = channels ----
    float4 bj[4];
#pragma unroll
    for (int j = 0; j < 4; ++j)
        bj[j] = *(const float4*)(bias + w * 64 + j * 16 + quad * 4);

#pragma unroll
    for (int i = 0; i < 4; ++i) {
        const int gm = m0 + i * 16 + mrow;
        if (gm >= VM) continue;
        const unsigned int b   = (unsigned int)gm / (unsigned int)LV;
        const unsigned int pix = (unsigned int)gm - b * (unsigned int)LV;
#pragma unroll
        for (int j = 0; j < 4; ++j) {
            const int ch = w * 64 + j * 16 + quad * 4;
            const int h  = ch >> 5, cc = ch & 31;
            uint2 o;
            o.x = pk2bf(acc[i][j][0] + bj[j].x, acc[i][j][1] + bj[j].y);
            o.y = pk2bf(acc[i][j][2] + bj[j].z, acc[i][j][3] + bj[j].w);
            *(uint2*)(v + (((size_t)(b * NH + h)) * LV + pix) * HD + cc) = o;
        }
    }
}

// ---------------------------------------------------------------------------
// oproj: d_out = out_head(bf16) @ op_w + op_b (f32 out). (validated)
// ---------------------------------------------------------------------------
__global__ __launch_bounds__(512, 2) void oproj_mfma_kernel(
    const unsigned short* __restrict__ Ah,   // [8192][256] bf16
    const unsigned short* __restrict__ opT,  // [256][256] bf16 [n][k]
    const float* __restrict__ bias,          // [256]
    float* __restrict__ out)                 // [8192][256] f32
{
    const int tid  = threadIdx.x;
    const int w    = tid >> 6;
    const int lane = tid & 63;
    const int mrow = lane & 15;
    const int quad = lane >> 4;
    const int m0   = blockIdx.x * 32;

    float4 bj[2];
#pragma unroll
    for (int j = 0; j < 2; ++j)
        bj[j] = *(const float4*)(bias + w * 32 + j * 16 + quad * 4);

    f32x4 acc[2][2];
#pragma unroll
    for (int i = 0; i < 2; ++i)
#pragma unroll
        for (int j = 0; j < 2; ++j) acc[i][j] = (f32x4)0.f;

#pragma unroll
    for (int kc = 0; kc < 8; ++kc) {
        bf16x8 wf[2], af[2];
#pragma unroll
        for (int j = 0; j < 2; ++j) {
            const int n = w * 32 + j * 16 + mrow;
            wf[j] = *(const bf16x8*)(const void*)(opT + (size_t)n * 256 + kc * 32 + quad * 8);
        }
#pragma unroll
        for (int i = 0; i < 2; ++i) {
            const int gm = m0 + i * 16 + mrow;
            af[i] = *(const bf16x8*)(const void*)(Ah + (size_t)gm * 256 + kc * 32 + quad * 8);
        }
#pragma unroll
        for (int i = 0; i < 2; ++i)
#pragma unroll
            for (int j = 0; j < 2; ++j)
                acc[i][j] = __builtin_amdgcn_mfma_f32_16x16x32_bf16(
                    wf[j], af[i], acc[i][j], 0, 0, 0);
    }

#pragma unroll
    for (int i = 0; i < 2; ++i) {
        const int gm = m0 + i * 16 + mrow;
#pragma unroll
        for (int j = 0; j < 2; ++j) {
            float4 o;
            o.x = acc[i][j][0] + bj[j].x;
            o.y = acc[i][j][1] + bj[j].y;
            o.z = acc[i][j][2] + bj[j].z;
            o.w = acc[i][j][3] + bj[j].w;
            *(float4*)(out + (size_t)gm * 256 + w * 32 + j * 16 + quad * 4) = o;
        }
    }
}

// ---------------------------------------------------------------------------
// Fused so+aw projection (f32 vector sgemm). A = query [8192][256].
// ---------------------------------------------------------------------------
__global__ __launch_bounds__(256) void qproj_kernel(
    const float* __restrict__ A,
    const float* __restrict__ so_w, const float* __restrict__ so_b,
    const float* __restrict__ aw_w, const float* __restrict__ aw_b,
    float* __restrict__ so_raw, float* __restrict__ aw_raw)
{
    __shared__ float As[16][68];
    __shared__ float Ws[16][68];

    const int tid = threadIdx.x;
    const int tx = tid & 15, ty = tid >> 4;
    const int m0 = blockIdx.y * 64;
    const int n0g = blockIdx.x * 64;

    const float* W; const float* bias; float* C; int N, n0;
    if (n0g < 256) { W = so_w; bias = so_b; C = so_raw; N = 256; n0 = n0g; }
    else           { W = aw_w; bias = aw_b; C = aw_raw; N = 128; n0 = n0g - 256; }

    const int ra = tid >> 2;
    const int ka = (tid & 3) << 2;
    const int rw = tid >> 4;
    const int cw = (tid & 15) << 2;

    float acc[4][4];
#pragma unroll
    for (int i = 0; i < 4; ++i)
#pragma unroll
        for (int j = 0; j < 4; ++j) acc[i][j] = 0.f;

    for (int k0 = 0; k0 < 256; k0 += 16) {
        const float4 av = *(const float4*)(A + (size_t)(m0 + ra) * 256 + (k0 + ka));
        As[ka + 0][ra] = av.x;
        As[ka + 1][ra] = av.y;
        As[ka + 2][ra] = av.z;
        As[ka + 3][ra] = av.w;
        *(float4*)&Ws[rw][cw] =
            *(const float4*)(W + (size_t)(k0 + rw) * N + (n0 + cw));
        __syncthreads();
#pragma unroll
        for (int k = 0; k < 16; ++k) {
            const float4 a4 = *(const float4*)&As[k][ty << 2];
            const float4 b4 = *(const float4*)&Ws[k][tx << 2];
            const float aa[4] = {a4.x, a4.y, a4.z, a4.w};
            const float bb[4] = {b4.x, b4.y, b4.z, b4.w};
#pragma unroll
            for (int i = 0; i < 4; ++i)
#pragma unroll
                for (int j = 0; j < 4; ++j)
                    acc[i][j] = fmaf(aa[i], bb[j], acc[i][j]);
        }
        __syncthreads();
    }

#pragma unroll
    for (int i = 0; i < 4; ++i) {
        const int row = m0 + (ty << 2) + i;
#pragma unroll
        for (int j = 0; j < 4; ++j) {
            const int col = n0 + (tx << 2) + j;
            C[(size_t)row * N + col] = acc[i][j] + bias[col];
        }
    }
}

// ---------------------------------------------------------------------------
// Sampling v3: one WAVE per (b,h,q). Lane = (pz: point-slot 0..7, ch:
// channel-group 0..7). 2 rounds x 4 independent corner gathers per lane;
// softmax + final accumulation via __shfl_xor (masks 8/16/32).
// Block 256 = 4 waves = 4 queries. Grid 16384, XCD-swizzled by (b,h).
// ---------------------------------------------------------------------------
__global__ __launch_bounds__(256) void sample_kernel(
    const unsigned short* __restrict__ v,   // [B][H][LV][32] bf16
    const float* __restrict__ so_raw,       // [B*Q][256]
    const float* __restrict__ aw_raw,       // [B*Q][128] raw logits
    const float* __restrict__ refp,         // [B][Q][4][2]
    unsigned short* __restrict__ out_head)  // [B*Q][256] bf16
{
    const int blk = blockIdx.x;
    const int xcd = blk & 7;
    const int j   = blk >> 3;              // 0..2047
    const int bh  = xcd * 8 + (j >> 8);    // blocks of same (b,h) contiguous per XCD
    const int qg  = j & 255;
    const int b   = bh >> 3;
    const int h   = bh & 7;

    const int wv   = threadIdx.x >> 6;     // wave = query
    const int lane = threadIdx.x & 63;
    const int ch   = lane & 7;             // channel group (4 ch)
    const int pz   = lane >> 3;            // point slot 0..7

    const int q  = qg * 4 + wv;
    const int rq = b * LQ + q;

    // ---- softmax over 16 points (each lane owns pz and pz+8) ----
    const float l0 = aw_raw[rq * 128 + h * 16 + pz];
    const float l1 = aw_raw[rq * 128 + h * 16 + 8 + pz];
    float mx = fmaxf(l0, l1);
    mx = fmaxf(mx, __shfl_xor(mx, 8));
    mx = fmaxf(mx, __shfl_xor(mx, 16));
    mx = fmaxf(mx, __shfl_xor(mx, 32));
    const float e0 = __expf(l0 - mx), e1 = __expf(l1 - mx);
    float sm = e0 + e1;
    sm += __shfl_xor(sm, 8);
    sm += __shfl_xor(sm, 16);
    sm += __shfl_xor(sm, 32);
    const float inv_s = 1.f / sm;

    const unsigned short* vb = v + (size_t)bh * (LV * HD) + ch * 4;

    float a0 = 0.f, a1 = 0.f, a2 = 0.f, a3 = 0.f;

#pragma unroll
    for (int r = 0; r < 2; ++r) {
        const int pt = r * 8 + pz;
        const int l  = pt >> 2;
        const int p  = pt & 3;
        const float wgt = (r ? e1 : e0) * inv_s;

        const int Wl = (l == 0) ? 100 : (l == 1) ? 50 : (l == 2) ? 25 : 13;
        const int st = (l == 0) ? 0 : (l == 1) ? 10000 : (l == 2) ? 12500 : 13125;
        const float invW = (l == 0) ? 0.01f : (l == 1) ? 0.02f : (l == 2) ? 0.04f
                                            : (1.0f / 13.0f);
        const float fw = (float)Wl;

        const float2 rxy = *(const float2*)(refp + (size_t)rq * 8 + l * 2);
        const float2 sxy = *(const float2*)(so_raw + (size_t)rq * 256 + h * 32 + l * 8 + p * 2);

        const float x = (rxy.x + sxy.x * invW) * fw - 0.5f;
        const float y = (rxy.y + sxy.y * invW) * fw - 0.5f;   // square levels

        const float xf = floorf(x), yf = floorf(y);
        const int x0 = (int)xf, y0 = (int)yf;
        const float wx1 = x - xf, wx0 = 1.f - wx1;
        const float wy1 = y - yf, wy0 = 1.f - wy1;

        const float vx0 = (x0 >= 0 && x0 < Wl) ? 1.f : 0.f;
        const float vx1 = (x0 + 1 >= 0 && x0 + 1 < Wl) ? 1.f : 0.f;
        const float vy0 = (y0 >= 0 && y0 < Wl) ? 1.f : 0.f;
        const float vy1 = (y0 + 1 >= 0 && y0 + 1 < Wl) ? 1.f : 0.f;

        const int xc0 = min(max(x0, 0), Wl - 1);
        const int xc1 = min(max(x0 + 1, 0), Wl - 1);
        const int yc0 = min(max(y0, 0), Wl - 1);
        const int yc1 = min(max(y0 + 1, 0), Wl - 1);

        const float w00 = wgt * wy0 * wx0 * vy0 * vx0;
        const float w01 = wgt * wy0 * wx1 * vy0 * vx1;
        const float w10 = wgt * wy1 * wx0 * vy1 * vx0;
        const float w11 = wgt * wy1 * wx1 * vy1 * vx1;

        const int row0 = (st + yc0 * Wl) * HD;
        const int row1 = (st + yc1 * Wl) * HD;

        const ushort4 u00 = *(const ushort4*)(vb + row0 + xc0 * HD);
        const ushort4 u01 = *(const ushort4*)(vb + row0 + xc1 * HD);
        const ushort4 u10 = *(const ushort4*)(vb + row1 + xc0 * HD);
        const ushort4 u11 = *(const ushort4*)(vb + row1 + xc1 * HD);

        a0 = fmaf(w00, bf2f(u00.x), a0);
        a1 = fmaf(w00, bf2f(u00.y), a1);
        a2 = fmaf(w00, bf2f(u00.z), a2);
        a3 = fmaf(w00, bf2f(u00.w), a3);
        a0 = fmaf(w01, bf2f(u01.x), a0);
        a1 = fmaf(w01, bf2f(u01.y), a1);
        a2 = fmaf(w01, bf2f(u01.z), a2);
        a3 = fmaf(w01, bf2f(u01.w), a3);
        a0 = fmaf(w10, bf2f(u10.x), a0);
        a1 = fmaf(w10, bf2f(u10.y), a1);
        a2 = fmaf(w10, bf2f(u10.z), a2);
        a3 = fmaf(w10, bf2f(u10.w), a3);
        a0 = fmaf(w11, bf2f(u11.x), a0);
        a1 = fmaf(w11, bf2f(u11.y), a1);
        a2 = fmaf(w11, bf2f(u11.z), a2);
        a3 = fmaf(w11, bf2f(u11.w), a3);
    }

    // ---- reduce over the 8 point-slots (preserves ch) ----
    a0 += __shfl_xor(a0, 8);  a1 += __shfl_xor(a1, 8);
    a2 += __shfl_xor(a2, 8);  a3 += __shfl_xor(a3, 8);
    a0 += __shfl_xor(a0, 16); a1 += __shfl_xor(a1, 16);
    a2 += __shfl_xor(a2, 16); a3 += __shfl_xor(a3, 16);
    a0 += __shfl_xor(a0, 32); a1 += __shfl_xor(a1, 32);
    a2 += __shfl_xor(a2, 32); a3 += __shfl_xor(a3, 32);

    if (pz == 0) {
        uint2 o;
        o.x = pk2bf(a0, a1);
        o.y = pk2bf(a2, a3);
        *(uint2*)(out_head + (size_t)rq * 256 + (h << 5) + (ch << 2)) = o;
    }
}

// ---------------------------------------------------------------------------
extern "C" void kernel_launch(void* const* d_in, const int* in_sizes, int n_in,
                              void* d_out, int out_size, void* d_ws, size_t ws_size,
                              hipStream_t stream)
{
    const float* query = (const float*)d_in[0];
    const float* refp  = (const float*)d_in[1];
    const float* value = (const float*)d_in[2];
    const float* so_w  = (const float*)d_in[4];
    const float* so_b  = (const float*)d_in[5];
    const float* aw_w  = (const float*)d_in[6];
    const float* aw_b  = (const float*)d_in[7];
    const float* vp_w  = (const float*)d_in[8];
    const float* vp_b  = (const float*)d_in[9];
    const float* op_w  = (const float*)d_in[10];
    const float* op_b  = (const float*)d_in[11];
    float* out = (float*)d_out;

    float* ws = (float*)d_ws;
    size_t off = 0;
    unsigned short* v = (unsigned short*)(ws + off);
    off += (size_t)BSZ * NH * LV * HD / 2;
    unsigned short* wTv = (unsigned short*)(ws + off); off += 32768;
    unsigned short* wTo = (unsigned short*)(ws + off); off += 32768;
    float* so_raw = ws + off; off += (size_t)BSZ * LQ * 256;
    float* aw_raw = ws + off; off += (size_t)BSZ * LQ * 128;
    unsigned short* out_head = (unsigned short*)(ws + off);
    off += (size_t)BSZ * LQ * 256 / 2;

    // 0) transpose+convert vp_w and op_w
    wconv_kernel<<<512, 256, 0, stream>>>(vp_w, op_w, wTv, wTo);

    // 1) value projection (barrier-free K-loop MFMA) -> v [b][h][pix][c]
    vproj_mfma_kernel<<<(VM + 63) / 64, 256, 0, stream>>>(value, wTv, vp_b, v);

    // 2) fused so+aw projection
    {
        dim3 grid(6, BSZ * LQ / 64);
        qproj_kernel<<<grid, 256, 0, stream>>>(query, so_w, so_b, aw_w, aw_b,
                                               so_raw, aw_raw);
    }
    // 3) deformable sampling (wave-per-query) -> out_head bf16
    sample_kernel<<<BSZ * NH * LQ / 4, 256, 0, stream>>>(
        v, so_raw, aw_raw, refp, out_head);

    // 4) output projection (MFMA) -> d_out
    oproj_mfma_kernel<<<BSZ * LQ / 32, 512, 0, stream>>>(out_head, wTo, op_b, out);
}

// Round 7
// 265.376 us; speedup vs baseline: 1.0381x; 1.0381x over previous
//
#include <hip/hip_runtime.h>
#include <hip/hip_bf16.h>
#include <math.h>

#define BSZ 8
#define LQ  1024
#define LV  13294
#define NH  8
#define HD  32
#define VM  (BSZ * LV)   // 106352 rows of value

typedef __attribute__((ext_vector_type(8))) short bf16x8;
typedef __attribute__((ext_vector_type(4))) float f32x4;

__device__ static inline unsigned short f2bf(float f) {
    unsigned int u = __float_as_uint(f);
    unsigned int r = (u + 0x7FFFu + ((u >> 16) & 1u)) >> 16;
    return (unsigned short)r;
}
__device__ static inline float bf2f(unsigned short s) {
    return __uint_as_float(((unsigned int)s) << 16);
}
__device__ static inline unsigned int pk2bf(float a, float b) {
    __hip_bfloat162 h = __float22bfloat162_rn(make_float2(a, b));
    return *(unsigned int*)&h;
}

// ---------------------------------------------------------------------------
// Weight prep:
//  blocks 0..255:   vp_w [k][n] f32 -> wTv [kc][n][kk] bf16 (kc=k>>5, kk=k&31)
//  blocks 256..511: op_w [k][n] f32 -> wTo [n][k] bf16
// ---------------------------------------------------------------------------
__global__ __launch_bounds__(256) void wconv_kernel(
    const float* __restrict__ w0, const float* __restrict__ w1,
    unsigned short* __restrict__ t0, unsigned short* __restrict__ t1)
{
    const int n = blockIdx.x & 255;
    const int k = threadIdx.x;
    if (blockIdx.x < 256) {
        const int kc = k >> 5, kk = k & 31;
        t0[((kc * 256 + n) << 5) + kk] = f2bf(w0[k * 256 + n]);
    } else {
        t1[n * 256 + k] = f2bf(w1[k * 256 + n]);
    }
}

// ---------------------------------------------------------------------------
// vproj v8: v = value @ vp_w + vp_b -> [b][h][pix][c] bf16.
// R6 structure (A in LDS once, single barrier, W direct from global in the
// K-loop) but with EVERY VMEM instruction coalesced:
//  - A staging: wave covers one 1KB row per 16B-lane load (16 lines/instr).
//  - W reads: [kc][n][kk] layout -> each (kc,j) read is 1KB contiguous.
// Swapped MFMA operands: lane = pix, regs = channels -> packed 8B stores.
// ---------------------------------------------------------------------------
__global__ __launch_bounds__(256, 4) void vproj_mfma_kernel(
    const float* __restrict__ A,            // [VM][256] f32
    const unsigned short* __restrict__ wT,  // [kc][n][kk] bf16
    const float* __restrict__ bias,         // [256]
    unsigned short* __restrict__ v)         // [B][H][LV][32] bf16
{
    __shared__ __align__(16) unsigned short Asb[64 * 256];  // 32 KB, swizzled

    const int tid  = threadIdx.x;
    const int w    = tid >> 6;
    const int lane = tid & 63;
    const int mrow = lane & 15;
    const int quad = lane >> 4;
    const int m0   = blockIdx.x * 64;

    // ---- stage A tile once, fully coalesced ----
    // round r: thread t loads the 16B f32 chunk at flat index r*256+t of the
    // 64KB tile (each wave = one whole 1KB row). Convert -> 8B bf16 into the
    // XOR-swizzled LDS layout (16B-bf16 chunk c = gcol>>1, half = gcol&1).
#pragma unroll
    for (int r = 0; r < 16; ++r) {
        const int flat = r * 256 + tid;
        const int grow = flat >> 6;
        const int gcol = flat & 63;           // 16B unit within the row
        int gm = m0 + grow; if (gm >= VM) gm = VM - 1;
        const float4 f = *(const float4*)(A + (size_t)gm * 256 + gcol * 4);
        uint2 pk;
        pk.x = pk2bf(f.x, f.y);
        pk.y = pk2bf(f.z, f.w);
        const int c  = gcol >> 1;
        const int cp = c ^ (grow & 31);
        *(uint2*)&Asb[grow * 256 + cp * 8 + (gcol & 1) * 4] = pk;
    }
    __syncthreads();

    // ---- K-loop: no barriers. W from global (coalesced, L2-hot). ----
    f32x4 acc[4][4];
#pragma unroll
    for (int i = 0; i < 4; ++i)
#pragma unroll
        for (int j = 0; j < 4; ++j) acc[i][j] = (f32x4)0.f;

#pragma unroll
    for (int kc = 0; kc < 8; ++kc) {
        bf16x8 wfr[4], af[4];
#pragma unroll
        for (int j = 0; j < 4; ++j) {
            const int n = w * 64 + j * 16 + mrow;
            wfr[j] = *(const bf16x8*)(const void*)(wT + (((size_t)kc * 256 + n) << 5) + quad * 8);
        }
#pragma unroll
        for (int i = 0; i < 4; ++i) {
            const int mr = i * 16 + mrow;
            const int cp = (kc * 4 + quad) ^ (mr & 31);
            af[i] = *(const bf16x8*)(const void*)&Asb[mr * 256 + cp * 8];
        }
#pragma unroll
        for (int i = 0; i < 4; ++i)
#pragma unroll
            for (int j = 0; j < 4; ++j)
                acc[i][j] = __builtin_amdgcn_mfma_f32_16x16x32_bf16(
                    wfr[j], af[i], acc[i][j], 0, 0, 0);
    }

    // ---- epilogue (validated): lane = pix, regs = channels ----
    float4 bj[4];
#pragma unroll
    for (int j = 0; j < 4; ++j)
        bj[j] = *(const float4*)(bias + w * 64 + j * 16 + quad * 4);

#pragma unroll
    for (int i = 0; i < 4; ++i) {
        const int gm = m0 + i * 16 + mrow;
        if (gm >= VM) continue;
        const unsigned int b   = (unsigned int)gm / (unsigned int)LV;
        const unsigned int pix = (unsigned int)gm - b * (unsigned int)LV;
#pragma unroll
        for (int j = 0; j < 4; ++j) {
            const int ch = w * 64 + j * 16 + quad * 4;
            const int h  = ch >> 5, cc = ch & 31;
            uint2 o;
            o.x = pk2bf(acc[i][j][0] + bj[j].x, acc[i][j][1] + bj[j].y);
            o.y = pk2bf(acc[i][j][2] + bj[j].z, acc[i][j][3] + bj[j].w);
            *(uint2*)(v + (((size_t)(b * NH + h)) * LV + pix) * HD + cc) = o;
        }
    }
}

// ---------------------------------------------------------------------------
// oproj: d_out = out_head(bf16) @ op_w + op_b (f32 out). (validated)
// ---------------------------------------------------------------------------
__global__ __launch_bounds__(512, 2) void oproj_mfma_kernel(
    const unsigned short* __restrict__ Ah,   // [8192][256] bf16
    const unsigned short* __restrict__ opT,  // [256][256] bf16 [n][k]
    const float* __restrict__ bias,          // [256]
    float* __restrict__ out)                 // [8192][256] f32
{
    const int tid  = threadIdx.x;
    const int w    = tid >> 6;
    const int lane = tid & 63;
    const int mrow = lane & 15;
    const int quad = lane >> 4;
    const int m0   = blockIdx.x * 32;

    float4 bj[2];
#pragma unroll
    for (int j = 0; j < 2; ++j)
        bj[j] = *(const float4*)(bias + w * 32 + j * 16 + quad * 4);

    f32x4 acc[2][2];
#pragma unroll
    for (int i = 0; i < 2; ++i)
#pragma unroll
        for (int j = 0; j < 2; ++j) acc[i][j] = (f32x4)0.f;

#pragma unroll
    for (int kc = 0; kc < 8; ++kc) {
        bf16x8 wf[2], af[2];
#pragma unroll
        for (int j = 0; j < 2; ++j) {
            const int n = w * 32 + j * 16 + mrow;
            wf[j] = *(const bf16x8*)(const void*)(opT + (size_t)n * 256 + kc * 32 + quad * 8);
        }
#pragma unroll
        for (int i = 0; i < 2; ++i) {
            const int gm = m0 + i * 16 + mrow;
            af[i] = *(const bf16x8*)(const void*)(Ah + (size_t)gm * 256 + kc * 32 + quad * 8);
        }
#pragma unroll
        for (int i = 0; i < 2; ++i)
#pragma unroll
            for (int j = 0; j < 2; ++j)
                acc[i][j] = __builtin_amdgcn_mfma_f32_16x16x32_bf16(
                    wf[j], af[i], acc[i][j], 0, 0, 0);
    }

#pragma unroll
    for (int i = 0; i < 2; ++i) {
        const int gm = m0 + i * 16 + mrow;
#pragma unroll
        for (int j = 0; j < 2; ++j) {
            float4 o;
            o.x = acc[i][j][0] + bj[j].x;
            o.y = acc[i][j][1] + bj[j].y;
            o.z = acc[i][j][2] + bj[j].z;
            o.w = acc[i][j][3] + bj[j].w;
            *(float4*)(out + (size_t)gm * 256 + w * 32 + j * 16 + quad * 4) = o;
        }
    }
}

// ---------------------------------------------------------------------------
// Fused so+aw projection (f32 vector sgemm). A = query [8192][256].
// ---------------------------------------------------------------------------
__global__ __launch_bounds__(256) void qproj_kernel(
    const float* __restrict__ A,
    const float* __restrict__ so_w, const float* __restrict__ so_b,
    const float* __restrict__ aw_w, const float* __restrict__ aw_b,
    float* __restrict__ so_raw, float* __restrict__ aw_raw)
{
    __shared__ float As[16][68];
    __shared__ float Ws[16][68];

    const int tid = threadIdx.x;
    const int tx = tid & 15, ty = tid >> 4;
    const int m0 = blockIdx.y * 64;
    const int n0g = blockIdx.x * 64;

    const float* W; const float* bias; float* C; int N, n0;
    if (n0g < 256) { W = so_w; bias = so_b; C = so_raw; N = 256; n0 = n0g; }
    else           { W = aw_w; bias = aw_b; C = aw_raw; N = 128; n0 = n0g - 256; }

    const int ra = tid >> 2;
    const int ka = (tid & 3) << 2;
    const int rw = tid >> 4;
    const int cw = (tid & 15) << 2;

    float acc[4][4];
#pragma unroll
    for (int i = 0; i < 4; ++i)
#pragma unroll
        for (int j = 0; j < 4; ++j) acc[i][j] = 0.f;

    for (int k0 = 0; k0 < 256; k0 += 16) {
        const float4 av = *(const float4*)(A + (size_t)(m0 + ra) * 256 + (k0 + ka));
        As[ka + 0][ra] = av.x;
        As[ka + 1][ra] = av.y;
        As[ka + 2][ra] = av.z;
        As[ka + 3][ra] = av.w;
        *(float4*)&Ws[rw][cw] =
            *(const float4*)(W + (size_t)(k0 + rw) * N + (n0 + cw));
        __syncthreads();
#pragma unroll
        for (int k = 0; k < 16; ++k) {
            const float4 a4 = *(const float4*)&As[k][ty << 2];
            const float4 b4 = *(const float4*)&Ws[k][tx << 2];
            const float aa[4] = {a4.x, a4.y, a4.z, a4.w};
            const float bb[4] = {b4.x, b4.y, b4.z, b4.w};
#pragma unroll
            for (int i = 0; i < 4; ++i)
#pragma unroll
                for (int j = 0; j < 4; ++j)
                    acc[i][j] = fmaf(aa[i], bb[j], acc[i][j]);
        }
        __syncthreads();
    }

#pragma unroll
    for (int i = 0; i < 4; ++i) {
        const int row = m0 + (ty << 2) + i;
#pragma unroll
        for (int j = 0; j < 4; ++j) {
            const int col = n0 + (tx << 2) + j;
            C[(size_t)row * N + col] = acc[i][j] + bias[col];
        }
    }
}

// ---------------------------------------------------------------------------
// Sampling v3 (validated R6): one WAVE per (b,h,q). Lane = (pz, ch).
// ---------------------------------------------------------------------------
__global__ __launch_bounds__(256) void sample_kernel(
    const unsigned short* __restrict__ v,   // [B][H][LV][32] bf16
    const float* __restrict__ so_raw,       // [B*Q][256]
    const float* __restrict__ aw_raw,       // [B*Q][128] raw logits
    const float* __restrict__ refp,         // [B][Q][4][2]
    unsigned short* __restrict__ out_head)  // [B*Q][256] bf16
{
    const int blk = blockIdx.x;
    const int xcd = blk & 7;
    const int j   = blk >> 3;
    const int bh  = xcd * 8 + (j >> 8);
    const int qg  = j & 255;
    const int b   = bh >> 3;
    const int h   = bh & 7;

    const int wv   = threadIdx.x >> 6;
    const int lane = threadIdx.x & 63;
    const int ch   = lane & 7;
    const int pz   = lane >> 3;

    const int q  = qg * 4 + wv;
    const int rq = b * LQ + q;

    const float l0 = aw_raw[rq * 128 + h * 16 + pz];
    const float l1 = aw_raw[rq * 128 + h * 16 + 8 + pz];
    float mx = fmaxf(l0, l1);
    mx = fmaxf(mx, __shfl_xor(mx, 8));
    mx = fmaxf(mx, __shfl_xor(mx, 16));
    mx = fmaxf(mx, __shfl_xor(mx, 32));
    const float e0 = __expf(l0 - mx), e1 = __expf(l1 - mx);
    float sm = e0 + e1;
    sm += __shfl_xor(sm, 8);
    sm += __shfl_xor(sm, 16);
    sm += __shfl_xor(sm, 32);
    const float inv_s = 1.f / sm;

    const unsigned short* vb = v + (size_t)bh * (LV * HD) + ch * 4;

    float a0 = 0.f, a1 = 0.f, a2 = 0.f, a3 = 0.f;

#pragma unroll
    for (int r = 0; r < 2; ++r) {
        const int pt = r * 8 + pz;
        const int l  = pt >> 2;
        const int p  = pt & 3;
        const float wgt = (r ? e1 : e0) * inv_s;

        const int Wl = (l == 0) ? 100 : (l == 1) ? 50 : (l == 2) ? 25 : 13;
        const int st = (l == 0) ? 0 : (l == 1) ? 10000 : (l == 2) ? 12500 : 13125;
        const float invW = (l == 0) ? 0.01f : (l == 1) ? 0.02f : (l == 2) ? 0.04f
                                            : (1.0f / 13.0f);
        const float fw = (float)Wl;

        const float2 rxy = *(const float2*)(refp + (size_t)rq * 8 + l * 2);
        const float2 sxy = *(const float2*)(so_raw + (size_t)rq * 256 + h * 32 + l * 8 + p * 2);

        const float x = (rxy.x + sxy.x * invW) * fw - 0.5f;
        const float y = (rxy.y + sxy.y * invW) * fw - 0.5f;

        const float xf = floorf(x), yf = floorf(y);
        const int x0 = (int)xf, y0 = (int)yf;
        const float wx1 = x - xf, wx0 = 1.f - wx1;
        const float wy1 = y - yf, wy0 = 1.f - wy1;

        const float vx0 = (x0 >= 0 && x0 < Wl) ? 1.f : 0.f;
        const float vx1 = (x0 + 1 >= 0 && x0 + 1 < Wl) ? 1.f : 0.f;
        const float vy0 = (y0 >= 0 && y0 < Wl) ? 1.f : 0.f;
        const float vy1 = (y0 + 1 >= 0 && y0 + 1 < Wl) ? 1.f : 0.f;

        const int xc0 = min(max(x0, 0), Wl - 1);
        const int xc1 = min(max(x0 + 1, 0), Wl - 1);
        const int yc0 = min(max(y0, 0), Wl - 1);
        const int yc1 = min(max(y0 + 1, 0), Wl - 1);

        const float w00 = wgt * wy0 * wx0 * vy0 * vx0;
        const float w01 = wgt * wy0 * wx1 * vy0 * vx1;
        const float w10 = wgt * wy1 * wx0 * vy1 * vx0;
        const float w11 = wgt * wy1 * wx1 * vy1 * vx1;

        const int row0 = (st + yc0 * Wl) * HD;
        const int row1 = (st + yc1 * Wl) * HD;

        const ushort4 u00 = *(const ushort4*)(vb + row0 + xc0 * HD);
        const ushort4 u01 = *(const ushort4*)(vb + row0 + xc1 * HD);
        const ushort4 u10 = *(const ushort4*)(vb + row1 + xc0 * HD);
        const ushort4 u11 = *(const ushort4*)(vb + row1 + xc1 * HD);

        a0 = fmaf(w00, bf2f(u00.x), a0);
        a1 = fmaf(w00, bf2f(u00.y), a1);
        a2 = fmaf(w00, bf2f(u00.z), a2);
        a3 = fmaf(w00, bf2f(u00.w), a3);
        a0 = fmaf(w01, bf2f(u01.x), a0);
        a1 = fmaf(w01, bf2f(u01.y), a1);
        a2 = fmaf(w01, bf2f(u01.z), a2);
        a3 = fmaf(w01, bf2f(u01.w), a3);
        a0 = fmaf(w10, bf2f(u10.x), a0);
        a1 = fmaf(w10, bf2f(u10.y), a1);
        a2 = fmaf(w10, bf2f(u10.z), a2);
        a3 = fmaf(w10, bf2f(u10.w), a3);
        a0 = fmaf(w11, bf2f(u11.x), a0);
        a1 = fmaf(w11, bf2f(u11.y), a1);
        a2 = fmaf(w11, bf2f(u11.z), a2);
        a3 = fmaf(w11, bf2f(u11.w), a3);
    }

    a0 += __shfl_xor(a0, 8);  a1 += __shfl_xor(a1, 8);
    a2 += __shfl_xor(a2, 8);  a3 += __shfl_xor(a3, 8);
    a0 += __shfl_xor(a0, 16); a1 += __shfl_xor(a1, 16);
    a2 += __shfl_xor(a2, 16); a3 += __shfl_xor(a3, 16);
    a0 += __shfl_xor(a0, 32); a1 += __shfl_xor(a1, 32);
    a2 += __shfl_xor(a2, 32); a3 += __shfl_xor(a3, 32);

    if (pz == 0) {
        uint2 o;
        o.x = pk2bf(a0, a1);
        o.y = pk2bf(a2, a3);
        *(uint2*)(out_head + (size_t)rq * 256 + (h << 5) + (ch << 2)) = o;
    }
}

// ---------------------------------------------------------------------------
extern "C" void kernel_launch(void* const* d_in, const int* in_sizes, int n_in,
                              void* d_out, int out_size, void* d_ws, size_t ws_size,
                              hipStream_t stream)
{
    const float* query = (const float*)d_in[0];
    const float* refp  = (const float*)d_in[1];
    const float* value = (const float*)d_in[2];
    const float* so_w  = (const float*)d_in[4];
    const float* so_b  = (const float*)d_in[5];
    const float* aw_w  = (const float*)d_in[6];
    const float* aw_b  = (const float*)d_in[7];
    const float* vp_w  = (const float*)d_in[8];
    const float* vp_b  = (const float*)d_in[9];
    const float* op_w  = (const float*)d_in[10];
    const float* op_b  = (const float*)d_in[11];
    float* out = (float*)d_out;

    float* ws = (float*)d_ws;
    size_t off = 0;
    unsigned short* v = (unsigned short*)(ws + off);
    off += (size_t)BSZ * NH * LV * HD / 2;
    unsigned short* wTv = (unsigned short*)(ws + off); off += 32768;
    unsigned short* wTo = (unsigned short*)(ws + off); off += 32768;
    float* so_raw = ws + off; off += (size_t)BSZ * LQ * 256;
    float* aw_raw = ws + off; off += (size_t)BSZ * LQ * 128;
    unsigned short* out_head = (unsigned short*)(ws + off);
    off += (size_t)BSZ * LQ * 256 / 2;

    // 0) weight prep
    wconv_kernel<<<512, 256, 0, stream>>>(vp_w, op_w, wTv, wTo);

    // 1) value projection (coalesced, barrier-free K-loop MFMA)
    vproj_mfma_kernel<<<(VM + 63) / 64, 256, 0, stream>>>(value, wTv, vp_b, v);

    // 2) fused so+aw projection
    {
        dim3 grid(6, BSZ * LQ / 64);
        qproj_kernel<<<grid, 256, 0, stream>>>(query, so_w, so_b, aw_w, aw_b,
                                               so_raw, aw_raw);
    }
    // 3) deformable sampling (wave-per-query) -> out_head bf16
    sample_kernel<<<BSZ * NH * LQ / 4, 256, 0, stream>>>(
        v, so_raw, aw_raw, refp, out_head);

    // 4) output projection (MFMA) -> d_out
    oproj_mfma_kernel<<<BSZ * LQ / 32, 512, 0, stream>>>(out_head, wTo, op_b, out);
}